// Round 15
// baseline (59.017 us; speedup 1.0000x reference)
//
#include <hip/hip_runtime.h>
#include <stdint.h>

#define S_GRID 7
#define N_CH 30
#define MAXB 8192          // max compacted boxes (actual data: 6272)
#define NTILE 32           // j-tiles (256 cols each)
#define NCHUNK 32          // i-chunks in match
#define CHUNK_MAX 256      // ceil(MAXB/NCHUNK) aligned to 4

// ---- ws layout (bytes) ----
// 0      : float acc[4] {xy+wh, obj, nobj, class}
// 16     : int finalCtr
// 64     : float pcls[128]   (per-prep-block class partials)
// 576    : float pnobj[128]  (per-prep-block noobj partials)
// 1024   : int ctr           (obj-cell allocator)
// 4096   : float4 PB4[MAXB]   (131072) -> 135168   {x0,y0,x1,y1}
// 135168 : float4 BT4[MAXB]   (131072) -> 266240
// 266240 : float  ConfP[MAXB] (32768)  -> 299008
// 299008 : u64 pkeys[NCHUNK][MAXB]  (2 MiB) -> 2396160

__global__ void k_prep(const float* __restrict__ P, const float* __restrict__ T, int ncell,
                       int* __restrict__ ctr,
                       float4* __restrict__ PB4, float4* __restrict__ BT4,
                       float* __restrict__ ConfP,
                       float* __restrict__ pcls, float* __restrict__ pnobj,
                       float* __restrict__ acc, int* __restrict__ finalCtr) {
    int b = blockIdx.x, tid = threadIdx.x;
    int gid = b * 256 + tid;

    // zero-init for k_final (block 0; plain stores, visible at dispatch boundary;
    // safe because NOTHING in k_prep touches acc/finalCtr via atomics)
    if (b == 0) {
        if (tid < 4)  acc[tid] = 0.0f;
        if (tid == 4) *finalCtr = 0;
    }

    int cell = gid;
    float2 pr[15], tr[15];
    if (cell < ncell) {
        const float2* p2 = (const float2*)(P + (size_t)cell * N_CH);
        const float2* t2 = (const float2*)(T + (size_t)cell * N_CH);
        #pragma unroll
        for (int k = 0; k < 15; ++k) { pr[k] = p2[k]; tr[k] = t2[k]; }
    } else {
        #pragma unroll
        for (int k = 0; k < 15; ++k) { pr[k] = make_float2(0.f, 0.f); tr[k] = make_float2(0.f, 0.f); }
    }
    bool obj = (cell < ncell) && (tr[2].x == 1.0f);   // t[4]

    int lane = tid & 63, wid = tid >> 6;
    unsigned long long bm = __ballot(obj);
    int wcnt = __popcll(bm);
    int base = 0;
    if (lane == 0 && wcnt) base = atomicAdd(ctr, wcnt);   // allocator only (not acc)
    base = __shfl(base, 0);

    float cls = 0.f, nob = 0.f;
    if (cell < ncell) {
        if (obj) {
            #pragma unroll
            for (int k = 5; k < 15; ++k) {            // floats 10..29
                float d0 = pr[k].x - tr[k].x, d1 = pr[k].y - tr[k].y;
                cls += d0 * d0 + d1 * d1;
            }
        } else {
            float d0 = pr[2].x - tr[2].x;             // p[4]-t[4]
            float d1 = pr[4].y - tr[4].y;             // p[9]-t[9]
            nob = d0 * d0 + d1 * d1;
        }
    }
    #pragma unroll
    for (int o = 32; o; o >>= 1) { cls += __shfl_down(cls, o); nob += __shfl_down(nob, o); }
    __shared__ float shC[4], shN[4];
    if (lane == 0) { shC[wid] = cls; shN[wid] = nob; }
    __syncthreads();
    if (tid == 0) {
        pcls[b]  = shC[0] + shC[1] + shC[2] + shC[3];   // plain stores, no race
        pnobj[b] = shN[0] + shN[1] + shN[2] + shN[3];
    }

    if (obj) {
        int rank = base + __popcll(bm & ((1ull << lane) - 1ull));
        float bx[2][5] = {
            { pr[0].x, pr[0].y, pr[1].x, pr[1].y, pr[2].x },
            { pr[2].y, pr[3].x, pr[3].y, pr[4].x, pr[4].y }
        };
        float tx[2][4] = {
            { tr[0].x, tr[0].y, tr[1].x, tr[1].y },
            { tr[2].y, tr[3].x, tr[3].y, tr[4].x }
        };
        #pragma unroll
        for (int bb = 0; bb < 2; ++bb) {
            int m = 2 * rank + bb;
            if (m < MAXB) {
                float cx = bx[bb][0] / (float)S_GRID, cy = bx[bb][1] / (float)S_GRID;
                float w = bx[bb][2], h = bx[bb][3];
                PB4[m] = make_float4(cx - 0.5f * w, cy - 0.5f * h, cx + 0.5f * w, cy + 0.5f * h);
                ConfP[m] = bx[bb][4];
                cx = tx[bb][0] / (float)S_GRID; cy = tx[bb][1] / (float)S_GRID;
                w = tx[bb][2]; h = tx[bb][3];
                BT4[m] = make_float4(cx - 0.5f * w, cy - 0.5f * h, cx + 0.5f * w, cy + 0.5f * h);
            }
        }
    }
}

// j-per-LANE match, LDS-staged chunk, branchless/division-free, NO ATOMICS:
//   iou_i > iou_best  <=>  inter_i*bS > bI*sum_i     (union = sum - inter)
// pad boxes {3,3,3,3} give inter=0, sum=ta>0 -> can never win once bI>=0,
// and the first real box (k=0) always beats the (-1,1) init. 19 VALU/box.
// Result stored as plain pkeys[c][j] (distinct addresses, full-rate stores).
__global__ void k_match(const float4* __restrict__ PB4, const float4* __restrict__ BT4,
                        const int* __restrict__ ctr,
                        unsigned long long* __restrict__ pkeys) {
    __shared__ float4 sh[CHUNK_MAX];
    int nb = 2 * (*ctr); if (nb > MAXB) nb = MAXB;
    int tid = threadIdx.x;
    int j = blockIdx.x * 256 + tid;
    if (blockIdx.x * 256 >= nb) return;      // whole tile beyond nb
    int c = blockIdx.y;
    int chunkLen = (((nb + NCHUNK - 1) / NCHUNK) + 3) & ~3;   // multiple of 4
    int i0 = c * chunkLen;
    int i1 = min(nb, i0 + chunkLen);
    if (i0 >= i1) return;

    int len = i1 - i0;
    int padded = (len + 3) & ~3;
    for (int k = tid; k < padded; k += 256)   // one pass (padded <= 256)
        sh[k] = (k < len) ? PB4[i0 + k] : make_float4(3.f, 3.f, 3.f, 3.f);
    __syncthreads();

    float4 tb = BT4[min(j, nb - 1)];          // per-lane target box (coalesced)
    float ta = (tb.z - tb.x) * (tb.w - tb.y);
    float bI = -1.f, bS = 1.f;                // first real box always wins
    int bidx = i0;

    float4 n0 = sh[0], n1 = sh[1], n2 = sh[2], n3 = sh[3];
    for (int kb = 0; kb < padded; kb += 4) {
        float4 b0 = n0, b1 = n1, b2 = n2, b3 = n3;
        int nx = kb + 4;
        if (nx < padded) { n0 = sh[nx]; n1 = sh[nx + 1]; n2 = sh[nx + 2]; n3 = sh[nx + 3]; }
        #define STEP(bb, kk)  {                                                     \
            float lx = fmaxf(tb.x, bb.x), ly = fmaxf(tb.y, bb.y);                   \
            float rx = fminf(tb.z, bb.z), ry = fminf(tb.w, bb.w);                   \
            float wx = fmaxf(rx - lx, 0.f), wy = fmaxf(ry - ly, 0.f);               \
            float inter = wx * wy;                                                  \
            float area = (bb.z - bb.x) * (bb.w - bb.y);                             \
            float sum = ta + area;                                                  \
            bool win = (inter * bS > bI * sum);                                     \
            bI   = win ? inter          : bI;                                       \
            bS   = win ? sum            : bS;                                       \
            bidx = win ? (i0 + kb + kk) : bidx;                                     \
        }
        STEP(b0, 0) STEP(b1, 1) STEP(b2, 2) STEP(b3, 3)
        #undef STEP
    }

    if (j < nb) {
        float iou = (bI >= 0.f) ? (bI / (bS - bI)) : 0.f;   // one precise divide
        unsigned long long key =
            ((unsigned long long)__float_as_uint(iou) << 32) |
            (unsigned long long)(0xFFFFFFFFu - (unsigned)bidx);
        pkeys[(size_t)c * MAXB + j] = key;   // plain store, no RMW
    }
}

// final: chunk-max over pkeys, box/conf losses, partial fold, ACQ_REL election.
// Reference gathers BOTH boxes by the argmax index: BPg=BP[idx], BTg=BT[idx].
__global__ void k_final(const float4* __restrict__ PB4, const float4* __restrict__ BT4,
                        const float* __restrict__ ConfP,
                        const int* __restrict__ ctr,
                        const unsigned long long* __restrict__ pkeys,
                        const float* __restrict__ pcls, const float* __restrict__ pnobj, int nblk,
                        float* __restrict__ acc, int* __restrict__ finalCtr,
                        float* __restrict__ out, float inv_batch) {
    int nb = 2 * (*ctr); if (nb > MAXB) nb = MAXB;
    int tid = threadIdx.x;
    int j = blockIdx.x * 256 + tid;
    float sxywh = 0.f, sobj = 0.f;
    if (j < nb) {
        int chunkLen = (((nb + NCHUNK - 1) / NCHUNK) + 3) & ~3;
        unsigned long long key = 0;
        #pragma unroll 4
        for (int c = 0; c < NCHUNK; ++c) {
            if (c * chunkLen >= nb) break;   // unwritten chunks
            unsigned long long k2 = pkeys[(size_t)c * MAXB + j];
            if (k2 > key) key = k2;          // bigger iou wins; ties -> smaller idx
        }
        float iou = __uint_as_float((unsigned)(key >> 32));
        unsigned idx = 0xFFFFFFFFu - (unsigned)(key & 0xFFFFFFFFull);
        float4 bp = PB4[idx];
        float4 bt = BT4[idx];                // by idx, matching the reference
        float cp = ConfP[idx];
        float dx = bp.x - bt.x, dy = bp.y - bt.y;
        float dw = sqrtf(bp.z) - sqrtf(bt.z);
        float dh = sqrtf(bp.w) - sqrtf(bt.w);
        sxywh = dx * dx + dy * dy + dw * dw + dh * dh;
        float dob = cp - iou;
        sobj = dob * dob;
    }
    // block 0 folds the per-prep-block class/noobj partials
    float exC = 0.f, exN = 0.f;
    if (blockIdx.x == 0 && tid < nblk) { exC = pcls[tid]; exN = pnobj[tid]; }

    #pragma unroll
    for (int o = 32; o; o >>= 1) {
        sxywh += __shfl_down(sxywh, o); sobj += __shfl_down(sobj, o);
        exC   += __shfl_down(exC, o);   exN  += __shfl_down(exN, o);
    }
    if ((tid & 63) == 0) {
        if (sxywh != 0.f) atomicAdd(&acc[0], sxywh);
        if (sobj != 0.f)  atomicAdd(&acc[1], sobj);
        if (exN != 0.f)   atomicAdd(&acc[2], exN);
        if (exC != 0.f)   atomicAdd(&acc[3], exC);
    }
    __syncthreads();                         // drains wave-leader atomics
    if (tid == 0) {
        int old = __hip_atomic_fetch_add(finalCtr, 1, __ATOMIC_ACQ_REL, __HIP_MEMORY_SCOPE_AGENT);
        if (old == NTILE - 1) {              // last block: all adds visible
            float a0 = __hip_atomic_load(&acc[0], __ATOMIC_RELAXED, __HIP_MEMORY_SCOPE_AGENT);
            float a1 = __hip_atomic_load(&acc[1], __ATOMIC_RELAXED, __HIP_MEMORY_SCOPE_AGENT);
            float a2 = __hip_atomic_load(&acc[2], __ATOMIC_RELAXED, __HIP_MEMORY_SCOPE_AGENT);
            float a3 = __hip_atomic_load(&acc[3], __ATOMIC_RELAXED, __HIP_MEMORY_SCOPE_AGENT);
            out[0] = (5.0f * a0 + 0.5f * a2 + a1 + a3) * inv_batch;
        }
    }
}

extern "C" void kernel_launch(void* const* d_in, const int* in_sizes, int n_in,
                              void* d_out, int out_size, void* d_ws, size_t ws_size,
                              hipStream_t stream) {
    const float* P = (const float*)d_in[0];
    const float* T = (const float*)d_in[1];
    int ncell = in_sizes[0] / N_CH;                 // 25088
    int batch = ncell / (S_GRID * S_GRID);          // 512

    char* ws = (char*)d_ws;
    float* acc      = (float*)ws;
    int*   finalCtr = (int*)(ws + 16);
    float* pcls     = (float*)(ws + 64);
    float* pnobj    = (float*)(ws + 576);
    int*   ctr      = (int*)(ws + 1024);
    float4* PB4  = (float4*)(ws + 4096);
    float4* BT4  = (float4*)(ws + 135168);
    float*  ConfP = (float*)(ws + 266240);
    unsigned long long* pkeys = (unsigned long long*)(ws + 299008);

    // ctr must start at 0: zero it via a tiny async memset-free trick is unavailable,
    // so reuse k_prep block 0? -> race (allocator used during prep). Dedicated 4B
    // fill via hipMemsetAsync is graph-legal (d2d) and tiny.
    hipMemsetAsync(ctr, 0, 4, stream);

    int nblk = (ncell + 255) / 256;                 // 98 (<=128 for pcls/pnobj)
    k_prep <<<nblk, 256, 0, stream>>>(P, T, ncell, ctr, PB4, BT4, ConfP,
                                      pcls, pnobj, acc, finalCtr);
    dim3 g3(NTILE, NCHUNK);                         // (32, 32); inactive blocks exit
    k_match<<<g3, 256, 0, stream>>>(PB4, BT4, ctr, pkeys);
    k_final<<<NTILE, 256, 0, stream>>>(PB4, BT4, ConfP, ctr, pkeys, pcls, pnobj, nblk,
                                       acc, finalCtr, (float*)d_out, 1.0f / (float)batch);
}